// Round 8
// baseline (248.155 us; speedup 1.0000x reference)
//
#include <hip/hip_runtime.h>

#define BB 8
#define C 64
#define HH 128
#define WW 128
#define HW (HH*WW)

#define TS 72        // LDS channel stride (ushorts): 144B rows; lanes land 2/bank on b128
#define NPX 324      // 18*18 halo tile pixels (16x16 tiles)
#define FNPX 340     // 10*34 halo tile pixels (convf 32x8 tiles)

typedef __attribute__((ext_vector_type(8))) short short8;
typedef __attribute__((ext_vector_type(4))) short short4v;
typedef __attribute__((ext_vector_type(4))) float f32x4;

__device__ inline unsigned short f2bf(float f) {
    union { float f; unsigned u; } v; v.f = f;
    unsigned r = v.u + 0x7fff + ((v.u >> 16) & 1);   // RNE
    return (unsigned short)(r >> 16);
}
__device__ inline float bf2f(unsigned short h) {
    union { unsigned u; float f; } v; v.u = ((unsigned)h) << 16;
    return v.f;
}

// ---------------------------------------------------------------------------
// Prep: wb[p][row][ci] bf16 for conv0/convf (row=oc) and wb3 (row'=j*64+oc);
// b3r[j][oc]; zero m.
// ---------------------------------------------------------------------------
__global__ __launch_bounds__(256) void prep_kernel(
    const float* __restrict__ w0, const float* __restrict__ wf,
    const float* __restrict__ w3, const float* __restrict__ b3,
    unsigned short* __restrict__ wb0, unsigned short* __restrict__ wbf,
    unsigned short* __restrict__ wb3, float* __restrict__ b3r,
    float* __restrict__ m)
{
    const int t = blockIdx.x * 256 + threadIdx.x;
    for (int i = t; i < C*C*9; i += 32*256) {
        int p = i % 9; int rest = i / 9; int ci = rest % C; int oc = rest / C;
        wb0[(p*C + oc)*C + ci] = f2bf(w0[i]);
        wbf[(p*C + oc)*C + ci] = f2bf(wf[i]);
    }
    for (int i = t; i < 9*C*C; i += 32*256) {        // dst: ((j*64+oc)*64+k)
        int j = i >> 12, oc = (i >> 6) & 63, k = i & 63;
        wb3[i] = f2bf(w3[(oc*9 + j)*C + k]);
    }
    for (int i = t; i < 9*C; i += 32*256) {          // b3r[j*64+oc] = b3[oc*9+j]
        int j = i >> 6, oc = i & 63;
        b3r[i] = b3[oc*9 + j];
    }
    for (int i = t; i < BB*C; i += 32*256) m[i] = 0.f;
}

// ---------------------------------------------------------------------------
// nhwc: x fp32 NCHW -> xb bf16 NHWC. Coalesced strided reads (256B/wave per
// channel), contiguous 16B writes. Removes conv0's 3x partial-line over-fetch.
// ---------------------------------------------------------------------------
__global__ __launch_bounds__(256) void nhwc_kernel(
    const float* __restrict__ x, unsigned short* __restrict__ xb)
{
    const int px = blockIdx.x * 256 + threadIdx.x;   // 0..131071
    const int b = px >> 14, pin = px & 16383;
    const float* sp = x + (size_t)b*C*HW + pin;
    unsigned short* dp = xb + (size_t)px*C;
#pragma unroll
    for (int g = 0; g < 8; ++g) {
        short8 o;
#pragma unroll
        for (int k = 0; k < 8; ++k) o[k] = (short)f2bf(sp[(size_t)(g*8+k)*HW]);
        *(short8*)&dp[g*8] = o;
    }
}

// ---------------------------------------------------------------------------
// conv0: MFMA implicit-GEMM, TRANSPOSED (M=oc, N=pixels). In: xb bf16 NHWC.
// Out: x0 bf16 NHWC (+bias). Fused mean: block-level pixel sum per oc ->
// atomicAdd into m (bias folded as +bias*256 per block).
// ---------------------------------------------------------------------------
__global__ __launch_bounds__(512) void conv0_kernel(
    const unsigned short* __restrict__ xb,
    const unsigned short* __restrict__ wb,   // [9][64][64] (row=oc, k=ci)
    const float* __restrict__ bias,
    unsigned short* __restrict__ x0g,        // [B,H,W,C] bf16
    float* __restrict__ msum)                // [B*C] (pre-zeroed)
{
    __shared__ unsigned short tile[NPX*TS];  // 46.7 KB
    __shared__ float red[8][64];             // 2 KB
    const int b  = blockIdx.z;
    const int h0 = blockIdx.y * 16;
    const int w0 = blockIdx.x * 16;
    const int t  = threadIdx.x;

    {
        const int pxi = t & 63, g = t >> 6;
        for (int px = pxi; px < NPX; px += 64) {
            int th = px / 18, tw = px - th*18;
            int gh = h0 + th - 1, gw = w0 + tw - 1;
            short8 v = {0,0,0,0,0,0,0,0};
            if ((unsigned)gh < HH && (unsigned)gw < WW)
                v = *(const short8*)&xb[((size_t)(b*HW) + gh*WW + gw)*C + g*8];
            *(short8*)&tile[px*TS + g*8] = v;
        }
    }
    __syncthreads();

    const int wid = t >> 6, ln = t & 63;
    const int l15 = ln & 15, q = ln >> 4;

    f32x4 acc[2][4];   // [nt(pixel rows)][mt(oc)]
#pragma unroll
    for (int nt = 0; nt < 2; ++nt)
#pragma unroll
        for (int mt = 0; mt < 4; ++mt) acc[nt][mt] = (f32x4){0.f,0.f,0.f,0.f};

#pragma unroll
    for (int p = 0; p < 9; ++p) {
        const int dh = p / 3, dw = p % 3;
#pragma unroll
        for (int ks = 0; ks < 2; ++ks) {
            short8 af[4];   // weights: A[m=oc][k=ci]
#pragma unroll
            for (int mt = 0; mt < 4; ++mt)
                af[mt] = *(const short8*)&wb[((size_t)(p*C) + mt*16 + l15)*C + ks*32 + q*8];
            short8 bf[2];   // pixels: B[k=ci][n=px]
#pragma unroll
            for (int nt = 0; nt < 2; ++nt)
                bf[nt] = *(const short8*)&tile[((wid*2+nt+dh)*18 + l15 + dw)*TS + ks*32 + q*8];
#pragma unroll
            for (int nt = 0; nt < 2; ++nt)
#pragma unroll
                for (int mt = 0; mt < 4; ++mt)
                    acc[nt][mt] = __builtin_amdgcn_mfma_f32_16x16x32_bf16(
                        af[mt], bf[nt], acc[nt][mt], 0, 0, 0);
        }
    }

    // epilogue: col=pixel(l15), row=oc(q*4+reg) -> NHWC dwordx2 stores
#pragma unroll
    for (int nt = 0; nt < 2; ++nt) {
        const int hh = h0 + wid*2 + nt;
        const size_t base = ((size_t)(b*HW) + hh*WW + w0 + l15)*C;
#pragma unroll
        for (int mt = 0; mt < 4; ++mt) {
            const int oc0 = mt*16 + q*4;
            const float4 bv = *(const float4*)&bias[oc0];
            unsigned u0 = (unsigned)f2bf(acc[nt][mt][0] + bv.x)
                        | ((unsigned)f2bf(acc[nt][mt][1] + bv.y) << 16);
            unsigned u1 = (unsigned)f2bf(acc[nt][mt][2] + bv.z)
                        | ((unsigned)f2bf(acc[nt][mt][3] + bv.w) << 16);
            uint2 uu; uu.x = u0; uu.y = u1;
            *(uint2*)&x0g[base + oc0] = uu;
        }
    }

    // fused mean: sum over this block's 256 pixels per oc
    f32x4 s[4];
#pragma unroll
    for (int mt = 0; mt < 4; ++mt)
#pragma unroll
        for (int reg = 0; reg < 4; ++reg)
            s[mt][reg] = acc[0][mt][reg] + acc[1][mt][reg];
#pragma unroll
    for (int mask = 1; mask < 16; mask <<= 1)
#pragma unroll
        for (int mt = 0; mt < 4; ++mt)
#pragma unroll
            for (int reg = 0; reg < 4; ++reg)
                s[mt][reg] += __shfl_xor(s[mt][reg], mask);
    if (l15 == 0) {
#pragma unroll
        for (int mt = 0; mt < 4; ++mt)
#pragma unroll
            for (int reg = 0; reg < 4; ++reg)
                red[wid][mt*16 + q*4 + reg] = s[mt][reg];
    }
    __syncthreads();
    if (t < 64) {
        float tot = bias[t] * 256.f;
#pragma unroll
        for (int w = 0; w < 8; ++w) tot += red[w][t];
        atomicAdd(&msum[b*C + t], tot);
    }
}

// ---------------------------------------------------------------------------
// fused_dyn: depthwise3x3 + ECA from the resident x0 LDS tile -> packed bf16
// A-matrix in LDS (XOR-swizzled) -> MFMA dynamic-filter GEMM + per-pixel
// dynamic conv + leaky -> y NHWC bf16. m arrives as SUMS (scale by 1/HW).
// ---------------------------------------------------------------------------
__global__ __launch_bounds__(512) void fused_dyn_kernel(
    const unsigned short* __restrict__ x0,
    const float* __restrict__ w1, const float* __restrict__ b1,
    const float* __restrict__ w2, const float* __restrict__ b2,
    const unsigned short* __restrict__ wb3,  // [(j*64+oc)][k]
    const float* __restrict__ b3r,           // [j*64+oc]
    const float* __restrict__ m,             // [B*C] sums (x0 incl. bias)
    unsigned short* __restrict__ yg)
{
    __shared__ unsigned short tile[NPX*TS];   // 46656 B
    __shared__ unsigned short alds[256*64];   // 32768 B  (A-matrix, swizzled)
    const int b  = blockIdx.z;
    const int h0 = blockIdx.y * 16;
    const int w0 = blockIdx.x * 16;
    const int t  = threadIdx.x;

    {
        const int pxi = t & 63, g = t >> 6;
        for (int px = pxi; px < NPX; px += 64) {
            int th = px / 18, tw = px - th*18;
            int gh = h0 + th - 1, gw = w0 + tw - 1;
            short8 v = {0,0,0,0,0,0,0,0};
            if ((unsigned)gh < HH && (unsigned)gw < WW)
                v = *(const short8*)&x0[((size_t)(b*HW) + gh*WW + gw)*C + g*8];
            *(short8*)&tile[px*TS + g*8] = v;
        }
    }
    __syncthreads();

    // ---- phase 1: depthwise + ECA for 32 channels of own pixel ----
    {
        const int px = t & 255, ghalf = t >> 8;
        const int r = px >> 4, cc = px & 15;
        const unsigned short* tb = tile + (r*18 + cc)*TS;
        const float w2a = w2[0], w2b = w2[1], w2c = w2[2], b2v = b2[0];
        const float inv = 1.f / (float)HW;
        const int sw = px & 7;
#pragma unroll
        for (int g = 0; g < 4; ++g) {
            const int octet = ghalf*4 + g;           // wave-uniform
            float dw8[8];
#pragma unroll
            for (int k = 0; k < 8; ++k) dw8[k] = 0.f;
#pragma unroll
            for (int j = 0; j < 9; ++j) {
                short8 v = *(const short8*)&tb[((j/3)*18 + (j%3))*TS + octet*8];
#pragma unroll
                for (int k = 0; k < 8; ++k)
                    dw8[k] = fmaf(w1[(octet*8+k)*9 + j],
                                  bf2f((unsigned short)v[k]), dw8[k]);
            }
            short8 o;
#pragma unroll
            for (int k = 0; k < 8; ++k) {
                const int c = octet*8 + k;
                const float mc = m[b*C + c] * inv;
                const float mp = (c > 0)  ? m[b*C + c - 1] * inv : 0.f;
                const float mn = (c < 63) ? m[b*C + c + 1] * inv : 0.f;
                const float att = fmaf(w2a, mp, fmaf(w2b, mc, fmaf(w2c, mn, b2v)));
                o[k] = (short)f2bf(dw8[k] + b1[c] + att);
            }
            *(short8*)&alds[px*64 + ((octet ^ sw) * 8)] = o;
        }
    }
    __syncthreads();

    // ---- phase 2: MFMA dynamic-filter GEMM + dynamic conv ----
    const int wid = t >> 6, ln = t & 63;
    const int l15 = ln & 15, q = ln >> 4;
    const int rl0 = (wid & 3) * 4;
    const int ogh = wid >> 2;

    short8 pfrag[4][2];
#pragma unroll
    for (int nt = 0; nt < 4; ++nt) {
        const int p = (rl0 + nt)*16 + l15;
        const int psw = p & 7;
#pragma unroll
        for (int ks = 0; ks < 2; ++ks)
            pfrag[nt][ks] = *(const short8*)&alds[p*64 + (((ks*4 + q) ^ psw) * 8)];
    }

#pragma unroll
    for (int ogi = 0; ogi < 2; ++ogi) {
        const int og = ogh*2 + ogi;
        f32x4 yac[4];
#pragma unroll
        for (int nt = 0; nt < 4; ++nt) yac[nt] = (f32x4){0.f,0.f,0.f,0.f};

        for (int j = 0; j < 9; ++j) {
            const int dh = j / 3, dw = j - dh*3;
            const f32x4 seed = *(const f32x4*)&b3r[j*64 + og*16 + q*4];
            const size_t abase = ((size_t)(j*64 + og*16 + l15))*C;
            const short8 a0 = *(const short8*)&wb3[abase + q*8];
            const short8 a1 = *(const short8*)&wb3[abase + 32 + q*8];
#pragma unroll
            for (int nt = 0; nt < 4; ++nt) {
                f32x4 fil = __builtin_amdgcn_mfma_f32_16x16x32_bf16(
                    a0, pfrag[nt][0], seed, 0, 0, 0);
                fil = __builtin_amdgcn_mfma_f32_16x16x32_bf16(
                    a1, pfrag[nt][1], fil, 0, 0, 0);
                const short4v pv = *(const short4v*)
                    &tile[((rl0+nt+dh)*18 + l15 + dw)*TS + og*16 + q*4];
#pragma unroll
                for (int reg = 0; reg < 4; ++reg)
                    yac[nt][reg] = fmaf(fil[reg],
                        bf2f((unsigned short)pv[reg]), yac[nt][reg]);
            }
        }

#pragma unroll
        for (int nt = 0; nt < 4; ++nt) {
            const size_t base = ((size_t)(b*HW) + (h0+rl0+nt)*WW + w0 + l15)*C;
            f32x4 v = yac[nt];
#pragma unroll
            for (int reg = 0; reg < 4; ++reg)
                v[reg] = (v[reg] >= 0.f) ? v[reg] : 0.2f * v[reg];
            unsigned u0 = (unsigned)f2bf(v[0]) | ((unsigned)f2bf(v[1]) << 16);
            unsigned u1 = (unsigned)f2bf(v[2]) | ((unsigned)f2bf(v[3]) << 16);
            uint2 uu; uu.x = u0; uu.y = u1;
            *(uint2*)&yg[base + og*16 + q*4] = uu;
        }
    }
}

// ---------------------------------------------------------------------------
// convf: MFMA implicit-GEMM (M=pixels, N=oc), 32w x 8h tiles so fp32 NCHW
// residual reads and output writes cover FULL 128B lines within one wave.
// In: y bf16 NHWC. Out: fp32 NCHW (+bias+residual).
// ---------------------------------------------------------------------------
__global__ __launch_bounds__(512) void convf_kernel(
    const unsigned short* __restrict__ yg,
    const unsigned short* __restrict__ wb,   // [9][64][64]
    const float* __restrict__ bias,
    const float* __restrict__ res,
    float* __restrict__ outg)
{
    __shared__ unsigned short tile[FNPX*TS];  // 340*144 = 47.8 KB
    const int b  = blockIdx.z;
    const int h0 = blockIdx.y * 8;
    const int w0 = blockIdx.x * 32;
    const int t  = threadIdx.x;

    {
        const int pxi = t & 63, g = t >> 6;
        for (int px = pxi; px < FNPX; px += 64) {
            int th = px / 34, tw = px - th*34;
            int gh = h0 + th - 1, gw = w0 + tw - 1;
            short8 v = {0,0,0,0,0,0,0,0};
            if ((unsigned)gh < HH && (unsigned)gw < WW)
                v = *(const short8*)&yg[((size_t)(b*HW) + gh*WW + gw)*C + g*8];
            *(short8*)&tile[px*TS + g*8] = v;
        }
    }
    __syncthreads();

    const int wid = t >> 6, ln = t & 63;     // wid = tile row 0..7
    const int l15 = ln & 15, q = ln >> 4;

    f32x4 acc[2][4];   // [mg(w half)][nt(oc)]
#pragma unroll
    for (int mg = 0; mg < 2; ++mg)
#pragma unroll
        for (int nt = 0; nt < 4; ++nt) acc[mg][nt] = (f32x4){0.f,0.f,0.f,0.f};

#pragma unroll
    for (int p = 0; p < 9; ++p) {
        const int dh = p / 3, dw = p % 3;
#pragma unroll
        for (int ks = 0; ks < 2; ++ks) {
            short8 bfrag[4];
#pragma unroll
            for (int nt = 0; nt < 4; ++nt)
                bfrag[nt] = *(const short8*)&wb[((size_t)(p*C) + nt*16 + l15)*C + ks*32 + q*8];
            short8 afrag[2];
#pragma unroll
            for (int mg = 0; mg < 2; ++mg)
                afrag[mg] = *(const short8*)&tile[((wid+dh)*34 + mg*16 + l15 + dw)*TS + ks*32 + q*8];
#pragma unroll
            for (int mg = 0; mg < 2; ++mg)
#pragma unroll
                for (int nt = 0; nt < 4; ++nt)
                    acc[mg][nt] = __builtin_amdgcn_mfma_f32_16x16x32_bf16(
                        afrag[mg], bfrag[nt], acc[mg][nt], 0, 0, 0);
        }
    }

    // epilogue: row(q*4+reg)=w offset within 16-seg, col(l15)=oc
#pragma unroll
    for (int mg = 0; mg < 2; ++mg) {
#pragma unroll
        for (int nt = 0; nt < 4; ++nt) {
            const int oc = nt*16 + l15;
            const float bv = bias[oc];
            const size_t base = (size_t)(b*C + oc)*HW + (h0+wid)*WW + w0 + mg*16 + q*4;
            const float4 rv = *(const float4*)&res[base];
            float4 ov;
            ov.x = acc[mg][nt][0] + bv + rv.x;
            ov.y = acc[mg][nt][1] + bv + rv.y;
            ov.z = acc[mg][nt][2] + bv + rv.z;
            ov.w = acc[mg][nt][3] + bv + rv.w;
            *(float4*)&outg[base] = ov;
        }
    }
}

extern "C" void kernel_launch(void* const* d_in, const int* in_sizes, int n_in,
                              void* d_out, int out_size, void* d_ws, size_t ws_size,
                              hipStream_t stream) {
    const float* x  = (const float*)d_in[0];
    const float* w0 = (const float*)d_in[1];
    const float* b0 = (const float*)d_in[2];
    const float* w1 = (const float*)d_in[3];
    const float* b1 = (const float*)d_in[4];
    const float* w2 = (const float*)d_in[5];
    const float* b2 = (const float*)d_in[6];
    const float* w3 = (const float*)d_in[7];
    const float* b3 = (const float*)d_in[8];
    const float* wf = (const float*)d_in[9];
    const float* bf = (const float*)d_in[10];
    float* out = (float*)d_out;

    unsigned short* x0  = (unsigned short*)d_ws;            // [B,H,W,C] bf16
    unsigned short* y   = x0  + (size_t)BB*HW*C;            // [B,H,W,C] bf16
    unsigned short* xb  = y   + (size_t)BB*HW*C;            // [B,H,W,C] bf16
    float*          m   = (float*)(xb + (size_t)BB*HW*C);   // [B*C]
    unsigned short* wb0 = (unsigned short*)(m + BB*C);
    unsigned short* wbf = wb0 + 9*C*C;
    unsigned short* wb3 = wbf + 9*C*C;
    float*          b3r = (float*)(wb3 + 9*C*C);

    prep_kernel<<<32, 256, 0, stream>>>(w0, wf, w3, b3, wb0, wbf, wb3, b3r, m);
    nhwc_kernel<<<512, 256, 0, stream>>>(x, xb);
    conv0_kernel<<<dim3(8,8,8), 512, 0, stream>>>(xb, wb0, b0, x0, m);
    fused_dyn_kernel<<<dim3(8,8,8), 512, 0, stream>>>(
        x0, w1, b1, w2, b2, wb3, b3r, m, y);
    convf_kernel<<<dim3(4,16,8), 512, 0, stream>>>(y, wbf, bf, x, out);
}